// Round 1
// 390.474 us; speedup vs baseline: 1.2455x; 1.2455x over previous
//
#include <hip/hip_runtime.h>

// CosineSelfAttention  B=4, S=8192, HID=768, NH=12, HD=64, EPS=1e-5
// Round 7: fuse K and V GEMMs into one block (shared A staging) and compute
// the per-head khat^T.v 64x64 partial IN the epilogue (LDS-transposed MFMA,
// kvacc-style). Kb/Vb never hit HBM; kvacc_k deleted. Deterministic fp32
// partials (one per 128-row tile) staged in d_out, reduced by kvred_k.
// ksum/vsum pre-reduced by redks_k so gemm_q preload is trivial.

typedef unsigned short u16;
typedef unsigned int u32;

#define B_ 4
#define S_ 8192
#define HID_ 768
#define NH_ 12
#define HD_ 64
#define EPS_ 1e-5f

typedef __attribute__((ext_vector_type(8))) short bf16x8;
typedef __attribute__((ext_vector_type(4))) float f32x4;

__device__ __forceinline__ float bf2f(unsigned int u) {
    u <<= 16;
    return __builtin_bit_cast(float, u);
}
__device__ __forceinline__ u16 f2bf(float f) {
    u32 u = __builtin_bit_cast(u32, f);
    u = u + 0x7fffu + ((u >> 16) & 1u);   // round-to-nearest-even
    return (u16)(u >> 16);
}

#define ASYNC16(gptr, lptr)                                                        \
    __builtin_amdgcn_global_load_lds(                                              \
        (const __attribute__((address_space(1))) void*)(gptr),                     \
        (__attribute__((address_space(3))) void*)(lptr), 16, 0, 0)

// ---------------------------------------------------------------------------
// Kernel 0: dtype sniff (1 = fp32, 0 = bf16)
// ---------------------------------------------------------------------------
__global__ void sniff_k(const void* __restrict__ X, u32* __restrict__ flag)
{
    __shared__ int bad;
    if (threadIdx.x == 0) bad = 0;
    __syncthreads();
    const u16* p = (const u16*)X;
    int loc = 0;
    for (int i = threadIdx.x; i < 8192; i += 256) {
        const u32 u = p[2 * i];
        const u32 e = (u >> 7) & 0xFFu;
        if (e >= 0xF8u) loc = 1;
    }
    if (loc) bad = 1;
    __syncthreads();
    if (threadIdx.x == 0) *flag = (u32)bad;
}

// ---------------------------------------------------------------------------
// Kernel 0b: convert X | Wq,Wk,Wv | mask | biases -> bf16 buffers.
// ---------------------------------------------------------------------------
__global__ __launch_bounds__(256) void conv_k(
    const void* __restrict__ X,
    const void* __restrict__ Wq, const void* __restrict__ Wk, const void* __restrict__ Wv,
    const void* __restrict__ bq, const void* __restrict__ bk, const void* __restrict__ bv,
    const void* __restrict__ mask,
    const u32* __restrict__ flagp,
    u16* __restrict__ Xb, u16* __restrict__ Wb, u16* __restrict__ Mb, u16* __restrict__ Bb)
{
    const int id = blockIdx.x;
    const void* src;
    u16* dst;
    int e;
    if (id < 12288) {                       // X
        src = X; dst = Xb; e = id * 2048 + threadIdx.x * 8;
    } else if (id < 13152) {                // W: 3 x 589824
        const int i = id - 12288;
        const int mat = i / 288;
        e = (i % 288) * 2048 + threadIdx.x * 8;
        src = (mat == 0) ? Wq : (mat == 1) ? Wk : Wv;
        dst = Wb + (size_t)mat * 589824;
    } else if (id < 13168) {                // mask: 32768
        const int i = id - 13152;
        src = mask; dst = Mb; e = i * 2048 + threadIdx.x * 8;
    } else {                                // biases: 3 x 768
        const int i = id - 13168;
        const int e0 = i * 2048 + threadIdx.x * 8;
        if (e0 >= 2304) return;
        const int mat = e0 / 768;
        src = (mat == 0) ? bq : (mat == 1) ? bk : bv;
        dst = Bb + mat * 768;
        e = e0 - mat * 768;
    }
    if (*flagp) {
        const float* s = (const float*)src + e;
        const float4 lo = *(const float4*)(s);
        const float4 hi = *(const float4*)(s + 4);
        uint4 o;
        o.x = (u32)f2bf(lo.x) | ((u32)f2bf(lo.y) << 16);
        o.y = (u32)f2bf(lo.z) | ((u32)f2bf(lo.w) << 16);
        o.z = (u32)f2bf(hi.x) | ((u32)f2bf(hi.y) << 16);
        o.w = (u32)f2bf(hi.z) | ((u32)f2bf(hi.w) << 16);
        *(uint4*)(dst + e) = o;
    } else {
        *(uint4*)(dst + e) = *(const uint4*)((const u16*)src + e);
    }
}

// ---------------------------------------------------------------------------
// Kernel 1: fused K+V GEMM (shared A staging) + kv-partial epilogue.
// 512 threads = 8 waves: wm = wid&3 (32-row group), wn = wid>>2 (head).
// Per block: K-tile and V-tile 128x128 (2 heads), then per-head 64x64
// khat^T.v partial via LDS-transposed MFMA. Also fp32 colsum partials
// (kspart masked+normed K, vspart raw V) from unrounded accumulators.
// ---------------------------------------------------------------------------
__global__ __launch_bounds__(512, 4) void gemm_kvf_k(
    const u16* __restrict__ Xb, const u16* __restrict__ Wb,
    const u16* __restrict__ Bb, const u16* __restrict__ Mb,
    float* __restrict__ kvpart, float* __restrict__ kspart, float* __restrict__ vspart)
{
    __shared__ u16 smem[32768];            // 64 KB: staging A|BK|BV (48K), then trans
    __shared__ float colsum[2][4][128];

    const int tid  = threadIdx.x;
    const int lane = tid & 63;
    const int wid  = tid >> 6;             // 0..7
    const int wm   = wid & 3;              // row group (32 rows)
    const int wn   = wid >> 2;             // head (64 cols)

    const int bid   = blockIdx.x;
    const int row_t = bid / 6;             // 0..255
    const int ncol  = bid % 6;
    const int b     = row_t >> 6;
    const int rt_b  = row_t & 63;
    const int arow0 = row_t * 128;
    const int brow0 = ncol * 128;
    const int bh0   = b * NH_ + ncol * 2;

    const u16* WK = Wb + 589824;
    const u16* WV = Wb + 2 * 589824;

    // staging mapping: 48 chunks (3 tiles x 16), 6 per wave; lptr wave-uniform
    const int gseg = (lane & 7) ^ ((lane >> 3) & 7);
    const u16* src6[6];
    int loff6[6];
#pragma unroll
    for (int t = 0; t < 6; ++t) {
        const int cg    = wid * 6 + t;
        const int tile  = cg >> 4;
        const int chunk = cg & 15;
        const int row   = chunk * 8 + (lane >> 3);
        const u16* base = (tile == 0) ? (Xb + (size_t)(arow0 + row) * HID_)
                        : (tile == 1) ? (WK + (size_t)(brow0 + row) * HID_)
                                      : (WV + (size_t)(brow0 + row) * HID_);
        src6[t]  = base + gseg * 8;
        loff6[t] = cg * 512;
    }

    f32x4 acc[2][2][4];
#pragma unroll
    for (int m = 0; m < 2; ++m)
#pragma unroll
        for (int i = 0; i < 2; ++i)
#pragma unroll
            for (int j = 0; j < 4; ++j) acc[m][i][j] = (f32x4){0.f, 0.f, 0.f, 0.f};

    for (int k0 = 0; k0 < HID_; k0 += 64) {
#pragma unroll
        for (int t = 0; t < 6; ++t)
            ASYNC16(src6[t] + k0, smem + loff6[t]);
        __syncthreads();
#pragma unroll
        for (int ks = 0; ks < 2; ++ks) {
            const int phys = ((ks * 4 + (lane >> 4)) ^ (lane & 7)) * 8;
            bf16x8 af[2];
#pragma unroll
            for (int i = 0; i < 2; ++i)
                af[i] = *(const bf16x8*)(smem + (wm * 32 + i * 16 + (lane & 15)) * 64 + phys);
            bf16x8 bfr[4];
#pragma unroll
            for (int j = 0; j < 4; ++j)
                bfr[j] = *(const bf16x8*)(smem + 8192 + (wn * 64 + j * 16 + (lane & 15)) * 64 + phys);
#pragma unroll
            for (int i = 0; i < 2; ++i)
#pragma unroll
                for (int j = 0; j < 4; ++j)
                    acc[0][i][j] = __builtin_amdgcn_mfma_f32_16x16x32_bf16(af[i], bfr[j], acc[0][i][j], 0, 0, 0);
#pragma unroll
            for (int j = 0; j < 4; ++j)
                bfr[j] = *(const bf16x8*)(smem + 16384 + (wn * 64 + j * 16 + (lane & 15)) * 64 + phys);
#pragma unroll
            for (int i = 0; i < 2; ++i)
#pragma unroll
                for (int j = 0; j < 4; ++j)
                    acc[1][i][j] = __builtin_amdgcn_mfma_f32_16x16x32_bf16(af[i], bfr[j], acc[1][i][j], 0, 0, 0);
        }
        __syncthreads();
    }

    // ---- bias
    float biasK[4], biasV[4];
#pragma unroll
    for (int j = 0; j < 4; ++j) {
        const int c = brow0 + wn * 64 + j * 16 + (lane & 15);
        biasK[j] = bf2f(Bb[768 + c]);
        biasV[j] = bf2f(Bb[1536 + c]);
    }
#pragma unroll
    for (int i = 0; i < 2; ++i)
#pragma unroll
        for (int j = 0; j < 4; ++j)
#pragma unroll
            for (int r = 0; r < 4; ++r) {
                acc[0][i][j][r] += biasK[j];
                acc[1][i][j][r] += biasV[j];
            }

    // ---- K: mask + cosine norm (per-head 64 cols = this wave's j range)
    float scale[2][4];
#pragma unroll
    for (int i = 0; i < 2; ++i) {
#pragma unroll
        for (int r = 0; r < 4; ++r) {
            float ss = 0.f;
#pragma unroll
            for (int j = 0; j < 4; ++j) ss += acc[0][i][j][r] * acc[0][i][j][r];
#pragma unroll
            for (int off = 1; off < 16; off <<= 1) ss += __shfl_xor(ss, off, 64);
            const int grow = arow0 + wm * 32 + i * 16 + (lane >> 4) * 4 + r;
            const float mk = bf2f(Mb[grow]);
            const float mf = (mk == 0.f) ? 1.f : 0.f;
            scale[i][r] = mf / (sqrtf(ss) + EPS_);
        }
    }

    // ---- fp32 column-sum partials (unrounded accumulators)
#pragma unroll
    for (int m = 0; m < 2; ++m) {
#pragma unroll
        for (int j = 0; j < 4; ++j) {
            float s = 0.f;
#pragma unroll
            for (int i = 0; i < 2; ++i)
#pragma unroll
                for (int r = 0; r < 4; ++r)
                    s += (m == 0) ? acc[0][i][j][r] * scale[i][r] : acc[1][i][j][r];
            s += __shfl_xor(s, 16, 64);
            s += __shfl_xor(s, 32, 64);
            if (lane < 16) colsum[m][wm][wn * 64 + j * 16 + lane] = s;
        }
    }

    // ---- transposed bf16 scatter into smem: [K h0 | K h1 | V h0 | V h1],
    //      each [d=64][s=128], s-seg XOR-swizzled by (d&7)
#pragma unroll
    for (int i = 0; i < 2; ++i)
#pragma unroll
        for (int j = 0; j < 4; ++j) {
            const int d = j * 16 + (lane & 15);
            u16* baseK = smem + wn * 8192 + d * 128;
            u16* baseV = smem + (2 + wn) * 8192 + d * 128;
#pragma unroll
            for (int r = 0; r < 4; ++r) {
                const int srow = wm * 32 + i * 16 + (lane >> 4) * 4 + r;
                const int sadr = ((((srow >> 3) ^ (d & 7)) << 3) | (srow & 7));
                baseK[sadr] = f2bf(acc[0][i][j][r] * scale[i][r]);
                baseV[sadr] = f2bf(acc[1][i][j][r]);
            }
        }
    __syncthreads();

    // ---- store ks/vs partials
    if (tid < 256) {
        const int m = tid >> 7, c = tid & 127;
        const float s = colsum[m][0][c] + colsum[m][1][c] + colsum[m][2][c] + colsum[m][3][c];
        (m ? vspart : kspart)[row_t * 768 + brow0 + c] = s;
    }

    // ---- kv partial: per wave (hd = wid&1, D = wid>>1): out[d=D*16..][e]
    const int hd = wid & 1;
    const int D  = wid >> 1;
    const u16* lK = smem + hd * 8192;
    const u16* lV = smem + (2 + hd) * 8192;
    f32x4 akv[4];
#pragma unroll
    for (int E = 0; E < 4; ++E) akv[E] = (f32x4){0.f, 0.f, 0.f, 0.f};
#pragma unroll
    for (int ks = 0; ks < 4; ++ks) {
        const int physs = ((ks * 4 + (lane >> 4)) ^ (lane & 7)) * 8;
        const bf16x8 ak = *(const bf16x8*)(lK + (D * 16 + (lane & 15)) * 128 + physs);
#pragma unroll
        for (int E = 0; E < 4; ++E) {
            const bf16x8 bv = *(const bf16x8*)(lV + (E * 16 + (lane & 15)) * 128 + physs);
            akv[E] = __builtin_amdgcn_mfma_f32_16x16x32_bf16(ak, bv, akv[E], 0, 0, 0);
        }
    }
    // layout: kvpart[bh][rt][d*64+e]
    float* dst = kvpart + ((size_t)(bh0 + hd) * 64 + rt_b) * 4096;
#pragma unroll
    for (int E = 0; E < 4; ++E)
#pragma unroll
        for (int r = 0; r < 4; ++r)
            dst[(D * 16 + (lane >> 4) * 4 + r) * 64 + E * 16 + (lane & 15)] = akv[E][r];
}

// ---------------------------------------------------------------------------
// Kernel 2: msum[b] = count of mask[b,s]==0
// ---------------------------------------------------------------------------
__global__ __launch_bounds__(256) void msum_k(const u16* __restrict__ Mb,
                                              float* __restrict__ msumws)
{
    const int b = blockIdx.x, tid = threadIdx.x;
    float loc = 0.f;
    for (int i = 0; i < 32; ++i) {
        const float mv = bf2f(Mb[b * S_ + i * 256 + tid]);
        loc += (mv == 0.f) ? 1.f : 0.f;
    }
#pragma unroll
    for (int off = 32; off > 0; off >>= 1) loc += __shfl_down(loc, off, 64);
    __shared__ float red[4];
    if ((tid & 63) == 0) red[tid >> 6] = loc;
    __syncthreads();
    if (tid == 0) msumws[b] = red[0] + red[1] + red[2] + red[3];
}

// ---------------------------------------------------------------------------
// Kernel 3: reduce 64 kv partials per (b,h). grid (48,4), float4 coalesced.
// ---------------------------------------------------------------------------
__global__ __launch_bounds__(256) void kvred_k(const float* __restrict__ kvpart,
                                               float* __restrict__ kvred)
{
    const int bh = blockIdx.x;
    const int base = blockIdx.y * 1024 + threadIdx.x * 4;
    const float* p = kvpart + (size_t)bh * 64 * 4096 + base;
    f32x4 s = (f32x4){0.f, 0.f, 0.f, 0.f};
    for (int rt = 0; rt < 64; ++rt)
        s += *(const f32x4*)(p + (size_t)rt * 4096);
    *(f32x4*)(kvred + (size_t)bh * 4096 + base) = s;
}

// ---------------------------------------------------------------------------
// Kernel 3b: reduce kspart/vspart [256][768] -> per-batch [4][768].
// grid (8,3): bx = m*4+b, by = col chunk.
// ---------------------------------------------------------------------------
__global__ __launch_bounds__(256) void redks_k(
    const float* __restrict__ kspart, const float* __restrict__ vspart,
    float* __restrict__ ksred, float* __restrict__ vsred)
{
    const int m = blockIdx.x >> 2, b = blockIdx.x & 3;
    const int c = blockIdx.y * 256 + threadIdx.x;
    const float* src = m ? vspart : kspart;
    float s = 0.f;
    for (int rt = 0; rt < 64; ++rt) s += src[(b * 64 + rt) * 768 + c];
    (m ? vsred : ksred)[b * 768 + c] = s;
}

// ---------------------------------------------------------------------------
// Kernel 4: Q GEMM + fused MFMA matvec epilogue -> fp32 out.
// Preload now reads pre-reduced kvred (hi/lo bf16 split) and ksred/vsred.
// ---------------------------------------------------------------------------
__global__ __launch_bounds__(256) void gemm_q_out_k(
    const u16* __restrict__ Xb, const u16* __restrict__ Wb,
    const u16* __restrict__ Bb, const u16* __restrict__ Mb,
    const float* __restrict__ kvred, const float* __restrict__ ksred,
    const float* __restrict__ vsred, const float* __restrict__ msumws,
    float* __restrict__ out)
{
    __shared__ u16 smem[128 * 64 * 2];      // staging A|B, then qn[128x128 swiz]
    __shared__ u16 ekvH[2 * 64 * 64];       // kv hi bf16: [hd][e][d swiz]
    __shared__ u16 ekvL[2 * 64 * 64];       // kv lo bf16
    __shared__ float ksl[2 * 64];
    __shared__ float vsl[2 * 64];
    __shared__ float dnl[2 * 128];
    u16* lA = smem;
    u16* lB = smem + 128 * 64;

    const int tid  = threadIdx.x;
    const int lane = tid & 63;
    const int wid  = tid >> 6;
    const int wm   = wid >> 1, wn = wid & 1;

    const int bid   = blockIdx.x;
    const int row_t = bid / 6;
    const int ncol  = bid % 6;
    const int b     = row_t >> 6;
    const int arow0 = row_t * 128;
    const int brow0 = ncol * 128;
    const int bh0   = b * NH_ + ncol * 2;

    // ---- preload kv (hi/lo bf16 split) and ksum/vsum (pre-reduced)
    for (int it = 0; it < 32; ++it) {
        const int idx = it * 256 + tid;          // 8192 = 2 heads x 64d x 64e
        const int hd = idx >> 12;
        const int de = idx & 4095;
        const int d = de >> 6, e = de & 63;
        const float v = kvred[(size_t)(bh0 + hd) * 4096 + de];
        const u16 hi = f2bf(v);
        const float rem = v - bf2f(hi);
        const int adr = hd * 4096 + e * 64 + ((((d >> 3) ^ (e & 7)) << 3) | (d & 7));
        ekvH[adr] = hi;
        ekvL[adr] = f2bf(rem);
    }
    if (tid < 128) {
        const int hd = tid >> 6, c = tid & 63;
        const int col = (ncol * 2 + hd) * 64 + c;
        ksl[tid] = ksred[b * 768 + col];
        vsl[tid] = vsred[b * 768 + col];
    }

    const int srow = lane >> 3;
    const int sseg = lane & 7;

    f32x4 acc[4][4];
#pragma unroll
    for (int i = 0; i < 4; ++i)
#pragma unroll
        for (int j = 0; j < 4; ++j) acc[i][j] = (f32x4){0.f, 0.f, 0.f, 0.f};

    for (int k0 = 0; k0 < HID_; k0 += 64) {
#pragma unroll
        for (int t = 0; t < 4; ++t) {
            const int chunk = wid * 4 + t;
            const int row = chunk * 8 + srow;
            const int gseg = sseg ^ (row & 7);
            ASYNC16(Xb + (size_t)(arow0 + row) * HID_ + k0 + gseg * 8, lA + chunk * 512);
            ASYNC16(Wb + (size_t)(brow0 + row) * HID_ + k0 + gseg * 8, lB + chunk * 512);
        }
        __syncthreads();
#pragma unroll
        for (int ks = 0; ks < 2; ++ks) {
            const int phys = ((ks * 4 + (lane >> 4)) ^ (lane & 7)) * 8;
            bf16x8 af[4], bfr[4];
#pragma unroll
            for (int i = 0; i < 4; ++i)
                af[i] = *(const bf16x8*)(lA + (wm * 64 + i * 16 + (lane & 15)) * 64 + phys);
#pragma unroll
            for (int j = 0; j < 4; ++j)
                bfr[j] = *(const bf16x8*)(lB + (wn * 64 + j * 16 + (lane & 15)) * 64 + phys);
#pragma unroll
            for (int i = 0; i < 4; ++i)
#pragma unroll
                for (int j = 0; j < 4; ++j)
                    acc[i][j] = __builtin_amdgcn_mfma_f32_16x16x32_bf16(af[i], bfr[j], acc[i][j], 0, 0, 0);
        }
        __syncthreads();
    }

    // ---- bias + mask + cosine norm
    float bias4[4];
#pragma unroll
    for (int j = 0; j < 4; ++j)
        bias4[j] = bf2f(Bb[brow0 + wn * 64 + j * 16 + (lane & 15)]);
#pragma unroll
    for (int i = 0; i < 4; ++i)
#pragma unroll
        for (int j = 0; j < 4; ++j)
#pragma unroll
            for (int r = 0; r < 4; ++r) acc[i][j][r] += bias4[j];

    float scale[4][4];
#pragma unroll
    for (int i = 0; i < 4; ++i) {
#pragma unroll
        for (int r = 0; r < 4; ++r) {
            float ss = 0.f;
#pragma unroll
            for (int j = 0; j < 4; ++j) ss += acc[i][j][r] * acc[i][j][r];
#pragma unroll
            for (int off = 1; off < 16; off <<= 1) ss += __shfl_xor(ss, off, 64);
            const int grow = arow0 + wm * 64 + i * 16 + (lane >> 4) * 4 + r;
            const float mk = bf2f(Mb[grow]);
            const float mf = (mk == 0.f) ? 1.f : 0.f;
            scale[i][r] = mf / (sqrtf(ss) + EPS_);
        }
    }

    // ---- repack qn bf16 into smem (swizzled), stride 128
#pragma unroll
    for (int i = 0; i < 4; ++i)
#pragma unroll
        for (int j = 0; j < 4; ++j)
#pragma unroll
            for (int r = 0; r < 4; ++r) {
                const int rr = wm * 64 + i * 16 + (lane >> 4) * 4 + r;
                const int cc = wn * 64 + j * 16 + (lane & 15);
                smem[rr * 128 + (((cc >> 3) ^ (rr & 7)) << 3) + (cc & 7)] =
                    f2bf(acc[i][j][r] * scale[i][r]);
            }
    __syncthreads();

    // ---- den = eps + msum + qn . ksum
    {
        const int row = tid & 127, hd = tid >> 7;
        float den = EPS_ + msumws[b];
#pragma unroll
        for (int c = 0; c < 8; ++c) {
            const int colbase = hd * 64 + c * 8;
            const int phys = (((colbase >> 3) ^ (row & 7)) << 3);
            const bf16x8 qv = *(const bf16x8*)(smem + row * 128 + phys);
#pragma unroll
            for (int m = 0; m < 8; ++m)
                den += bf2f((u16)qv[m]) * ksl[colbase + m];
        }
        dnl[hd * 128 + row] = 1.f / den;
    }
    __syncthreads();

    // ---- MFMA matvec: o = qn @ (kvH + kvL)  (head = wn)
    f32x4 o4[4][4];
#pragma unroll
    for (int i = 0; i < 4; ++i)
#pragma unroll
        for (int j = 0; j < 4; ++j) o4[i][j] = (f32x4){0.f, 0.f, 0.f, 0.f};
#pragma unroll
    for (int ks = 0; ks < 2; ++ks) {
        bf16x8 aq[4], bkH[4], bkL[4];
#pragma unroll
        for (int i = 0; i < 4; ++i) {
            const int row = wm * 64 + i * 16 + (lane & 15);
            const int colbase = wn * 64 + ks * 32 + (lane >> 4) * 8;
            const int phys = (((colbase >> 3) ^ (row & 7)) << 3);
            aq[i] = *(const bf16x8*)(smem + row * 128 + phys);
        }
#pragma unroll
        for (int j = 0; j < 4; ++j) {
            const int e = j * 16 + (lane & 15);
            const int physd = (((ks * 4 + (lane >> 4)) ^ (e & 7)) << 3);
            bkH[j] = *(const bf16x8*)(ekvH + wn * 4096 + e * 64 + physd);
            bkL[j] = *(const bf16x8*)(ekvL + wn * 4096 + e * 64 + physd);
        }
#pragma unroll
        for (int i = 0; i < 4; ++i)
#pragma unroll
            for (int j = 0; j < 4; ++j) {
                o4[i][j] = __builtin_amdgcn_mfma_f32_16x16x32_bf16(aq[i], bkH[j], o4[i][j], 0, 0, 0);
                o4[i][j] = __builtin_amdgcn_mfma_f32_16x16x32_bf16(aq[i], bkL[j], o4[i][j], 0, 0, 0);
            }
    }

    // ---- + vsum, x 1/den, store fp32
#pragma unroll
    for (int i = 0; i < 4; ++i) {
#pragma unroll
        for (int r = 0; r < 4; ++r) {
            const int row = wm * 64 + i * 16 + (lane >> 4) * 4 + r;
            const float inv = dnl[wn * 128 + row];
            float* op = out + (size_t)(arow0 + row) * HID_ + brow0 + wn * 64;
#pragma unroll
            for (int j = 0; j < 4; ++j) {
                const int e = j * 16 + (lane & 15);
                op[e] = (o4[i][j][r] + vsl[wn * 64 + e]) * inv;
            }
        }
    }
}

// ---------------------------------------------------------------------------
extern "C" void kernel_launch(void* const* d_in, const int* in_sizes, int n_in,
                              void* d_out, int out_size, void* d_ws, size_t ws_size,
                              hipStream_t stream) {
    const void* X   = d_in[0];
    const void* msk = d_in[1];
    const void* Wq  = d_in[2];
    const void* bq  = d_in[3];
    const void* Wk  = d_in[4];
    const void* bk  = d_in[5];
    const void* Wv  = d_in[6];
    const void* bv  = d_in[7];

    char* ws = (char*)d_ws;
    float* kvredw = (float*)ws;                         // 48*4096 = 786 KB
    float* kspart = kvredw + 48 * 4096;                 // 256*768 = 0.75 MB
    float* vspart = kspart + 256 * 768;                 // 0.75 MB
    float* ksred  = vspart + 256 * 768;                 // 4*768
    float* vsred  = ksred + 4 * 768;                    // 4*768
    float* msumws = vsred + 4 * 768;                    // 4
    u32*   flagp  = (u32*)(msumws + 4);
    u16* Xb = (u16*)(ws + (4 << 20));                   // 48 MB
    u16* Wb = Xb + (size_t)25165824;                    // 3.375 MB
    u16* Mb = Wb + (size_t)1769472;                     // 64 KB
    u16* Bb = Mb + (size_t)32768;                       // small

    float* kvpart = (float*)d_out;                      // 50.3 MB fp32 partials
                                                        // (consumed by kvred_k
                                                        // before gemm_q writes)

    hipLaunchKernelGGL(sniff_k, dim3(1), dim3(256), 0, stream, X, flagp);
    hipLaunchKernelGGL(conv_k, dim3(13170), dim3(256), 0, stream,
                       X, Wq, Wk, Wv, bq, bk, bv, msk, flagp, Xb, Wb, Mb, Bb);
    hipLaunchKernelGGL(gemm_kvf_k, dim3(1536), dim3(512), 0, stream,
                       Xb, Wb, Bb, Mb, kvpart, kspart, vspart);
    hipLaunchKernelGGL(msum_k, dim3(4), dim3(256), 0, stream, Mb, msumws);
    hipLaunchKernelGGL(kvred_k, dim3(48, 4), dim3(256), 0, stream, kvpart, kvredw);
    hipLaunchKernelGGL(redks_k, dim3(8, 3), dim3(256), 0, stream,
                       kspart, vspart, ksred, vsred);
    hipLaunchKernelGGL(gemm_q_out_k, dim3(1536), dim3(256), 0, stream,
                       Xb, Wb, Bb, Mb, kvredw, ksred, vsred, msumws, (float*)d_out);
}